// Round 5
// baseline (129.794 us; speedup 1.0000x reference)
//
#include <hip/hip_runtime.h>

// Depthwise Gaussian blur K=121, replicate pad, separable, fp32.
// R5: blur_v stages via global_load_lds (16B async DMA, weights-exp overlaps)
// and writes tmp WITH the 648-col replicate halo materialized; blur_h then
// stages pure float4->b128 (no clamp math, 4x fewer staging insts). Compute
// loops identical to R4 (known-good).

#define HH    512
#define WW    512
#define PLANE (512 * 512)
#define NIMG  24
#define RAD   60
#define TROW  648                 // tmp row: 60 left halo + 512 + 76 right
#define TPLANE (512 * TROW)

__device__ __forceinline__ void make_weights(const float* __restrict__ sigma,
                                             float* __restrict__ wlds, int tid) {
    const float s = sigma[0] * 8.0f + 16.0f;
    const float inv2v = 1.0f / (2.0f * s * s);
    float sum = 0.0f;
    #pragma unroll
    for (int k = 0; k <= 120; ++k) {
        const float c = (float)k - 60.0f;
        sum += __expf(-c * c * inv2v);
    }
    if (tid < 128) {
        float g = 0.0f;
        if (tid < 121) {
            const float c = (float)tid - 60.0f;
            g = __expf(-c * c * inv2v);
        }
        wlds[tid] = g / sum;   // taps 121..127 exactly 0
    }
}

// ---------------- vertical pass ----------------------------------------------
#define V_OCT(CUR, NXT, KO)                                               \
    { *(float4*)&wq[0] = *(const float4*)&wlds[(KO) * 8];                 \
      *(float4*)&wq[4] = *(const float4*)&wlds[(KO) * 8 + 4];             \
      _Pragma("unroll")                                                   \
      for (int ki = 0; ki < 8; ++ki) {                                    \
          NXT[ki] = sm4[(r0 + ((KO) + 1) * 8 + ki) * 8 + tx];             \
          const float wk = wq[ki];                                        \
          _Pragma("unroll")                                               \
          for (int j = 0; j < 8; ++j) {                                   \
              const int idx = ki + j;                                     \
              const float4 v = (idx < 8) ? CUR[idx] : NXT[idx - 8];       \
              acc[j].x += wk * v.x; acc[j].y += wk * v.y;                 \
              acc[j].z += wk * v.z; acc[j].w += wk * v.w;                 \
          }                                                               \
      }                                                                   \
    }

__global__ __launch_bounds__(256, 3) void blur_v(
        const float* __restrict__ x, const float* __restrict__ sigma,
        float* __restrict__ tmp) {
    __shared__ float sm[384 * 32];                   // 48 KB -> 3 blocks/CU
    __shared__ float wlds[128];
    const int tid = threadIdx.x;
    const int w0  = blockIdx.x * 32;
    const int h0  = blockIdx.y * 256;
    const float* __restrict__ src = x + (size_t)blockIdx.z * PLANE;

    // async DMA staging: 384 rows x 32 cols; lane layout = uniform base+lane*16
    {
        const int fc   = (tid & 7) * 4;
        const int wave = tid >> 6;
        int r = tid >> 3;                            // 0..31, +32/iter
        #pragma unroll
        for (int it = 0; it < 12; ++it, r += 32) {
            int gr = h0 - RAD + r;
            gr = gr < 0 ? 0 : (gr > HH - 1 ? HH - 1 : gr);
            const float* gp = &src[(size_t)gr * WW + w0 + fc];
            float* lp = &sm[1024 * it + 256 * wave];     // wave-uniform base
            __builtin_amdgcn_global_load_lds(
                (const __attribute__((address_space(1))) unsigned int*)gp,
                (__attribute__((address_space(3))) unsigned int*)lp,
                16, 0, 0);
        }
    }
    make_weights(sigma, wlds, tid);                  // overlaps DMA in flight
    __syncthreads();

    const int tx = tid & 7;
    const int r0 = (tid >> 3) * 8;
    const float4* __restrict__ sm4 = (const float4*)sm;

    float4 acc[8];
    #pragma unroll
    for (int j = 0; j < 8; ++j) acc[j] = make_float4(0.f, 0.f, 0.f, 0.f);

    float4 wa[8], wb[8];
    float  wq[8];
    #pragma unroll
    for (int m = 0; m < 8; ++m) wa[m] = sm4[(r0 + m) * 8 + tx];

    #pragma unroll 1
    for (int ko = 0; ko < 16; ko += 2) {
        V_OCT(wa, wb, ko)
        V_OCT(wb, wa, ko + 1)
    }

    // store shifted +60 into halo-materialized tmp rows (stride 648)
    float* __restrict__ dst = tmp + (size_t)blockIdx.z * TPLANE;
    #pragma unroll
    for (int j = 0; j < 8; ++j)
        *(float4*)&dst[(size_t)(h0 + r0 + j) * TROW + 60 + w0 + tx * 4] = acc[j];

    // left halo: cols 0..59 = vblur(col 0); right halo: 572..647 = vblur(col 511)
    if (blockIdx.x == 0 && tx == 0) {
        #pragma unroll
        for (int j = 0; j < 8; ++j) {
            const float v = acc[j].x;
            const float4 q = make_float4(v, v, v, v);
            float* p = dst + (size_t)(h0 + r0 + j) * TROW;
            #pragma unroll
            for (int t = 0; t < 15; ++t) ((float4*)p)[t] = q;
        }
    }
    if (blockIdx.x == (WW / 32) - 1 && tx == 7) {
        #pragma unroll
        for (int j = 0; j < 8; ++j) {
            const float v = acc[j].w;
            const float4 q = make_float4(v, v, v, v);
            float* p = dst + (size_t)(h0 + r0 + j) * TROW + 572;
            #pragma unroll
            for (int t = 0; t < 19; ++t) ((float4*)p)[t] = q;
        }
    }
}

// ---------------- horizontal pass --------------------------------------------
// 8 rows/block. Halo rows pre-materialized in tmp (648 cols) -> staging is
// pure float4 load + b128 LDS write into 81x(8+4pad)-float groups (row 972).
#define HPG_ROW 972

#define LOADG(DST, G)                                                     \
    { *(float4*)&DST[0] = *(const float4*)&bs[(G) * 12];                  \
      *(float4*)&DST[4] = *(const float4*)&bs[(G) * 12 + 4]; }

#define H_OCT(W0, W1, W2, W3, KO)                                         \
    { LOADG(W3, (KO) + 3)                                                 \
      *(float4*)&wq[0] = *(const float4*)&wlds[(KO) * 8];                 \
      *(float4*)&wq[4] = *(const float4*)&wlds[(KO) * 8 + 4];             \
      _Pragma("unroll")                                                   \
      for (int ki = 0; ki < 8; ++ki) {                                    \
          const float wk = wq[ki];                                        \
          _Pragma("unroll")                                               \
          for (int j = 0; j < 16; ++j) {                                  \
              const int idx = ki + j;                                     \
              const float v = (idx < 8) ? W0[idx]                         \
                            : (idx < 16) ? W1[idx - 8] : W2[idx - 16];    \
              acc[j] += wk * v;                                           \
          }                                                               \
      }                                                                   \
    }

__global__ __launch_bounds__(256, 4) void blur_h(
        const float* __restrict__ tmp, const float* __restrict__ sigma,
        float* __restrict__ out) {
    __shared__ float sm[8 * HPG_ROW];                // 31.1 KB -> 4 blocks/CU
    __shared__ float wlds[128];
    const int tid = threadIdx.x;
    const int h0  = blockIdx.x * 8;
    const float* __restrict__ src = tmp + (size_t)blockIdx.y * TPLANE;

    // stage 8 rows x 162 float4 (no clamps, vector loads, b128 LDS writes)
    for (int i = tid; i < 8 * 162; i += 256) {
        const int r = i / 162;
        const int s = i - r * 162;
        const int c = s * 4;
        const float4 v = *(const float4*)&src[(size_t)(h0 + r) * TROW + c];
        *(float4*)&sm[r * HPG_ROW + (c >> 3) * 12 + (c & 7)] = v;
    }
    make_weights(sigma, wlds, tid);
    __syncthreads();

    const int r = tid >> 5;                          // 0..7
    const int L = tid & 31;                          // cols 16L..16L+15
    const float* __restrict__ bs = sm + r * HPG_ROW + L * 24;  // group 2L

    float w0[8], w1[8], w2[8], w3[8], wq[8];
    float acc[16];
    #pragma unroll
    for (int j = 0; j < 16; ++j) acc[j] = 0.0f;

    LOADG(w0, 0)
    LOADG(w1, 1)
    LOADG(w2, 2)

    #pragma unroll 1
    for (int ko = 0; ko < 16; ko += 4) {
        H_OCT(w0, w1, w2, w3, ko)
        H_OCT(w1, w2, w3, w0, ko + 1)
        H_OCT(w2, w3, w0, w1, ko + 2)
        H_OCT(w3, w0, w1, w2, ko + 3)
    }

    float* __restrict__ dst = out + (size_t)blockIdx.y * PLANE
                                  + (size_t)(h0 + r) * WW + L * 16;
    *(float4*)(dst)      = make_float4(acc[0],  acc[1],  acc[2],  acc[3]);
    *(float4*)(dst + 4)  = make_float4(acc[4],  acc[5],  acc[6],  acc[7]);
    *(float4*)(dst + 8)  = make_float4(acc[8],  acc[9],  acc[10], acc[11]);
    *(float4*)(dst + 12) = make_float4(acc[12], acc[13], acc[14], acc[15]);
}

// ---------------- launch -----------------------------------------------------
extern "C" void kernel_launch(void* const* d_in, const int* in_sizes, int n_in,
                              void* d_out, int out_size, void* d_ws, size_t ws_size,
                              hipStream_t stream) {
    const float* x     = (const float*)d_in[0];
    const float* sigma = (const float*)d_in[1];
    float* out = (float*)d_out;
    float* tmp = (float*)d_ws;                       // 24*512*648 floats, 31.9 MB

    blur_v<<<dim3(WW / 32, HH / 256, NIMG), dim3(256), 0, stream>>>(x, sigma, tmp);
    blur_h<<<dim3(HH / 8, NIMG), dim3(256), 0, stream>>>(tmp, sigma, out);
}